// Round 1
// baseline (100.897 us; speedup 1.0000x reference)
//
#include <hip/hip_runtime.h>
#include <float.h>

#define D_DIM 1024
#define T_DIM 1024
#define B_DIM 16
#define NTOP 5
#define RAD 32              // exp(-k^2/8) == 0.0f in fp32 for |k| >= 29; 32 is safely exact
#define NORM_C 0.19947114f  // np.float32(1/(2*sqrt(2*pi)))
#define THRESH 2.0f         // 5th order stat of 1024 N(0,1) ~ 2.6; P(<5 qualifiers) ~ 3e-7/row
#define CAP 64              // max candidates/row handled on fast path (mean ~23)

// Stage 1: one wave per row. Threshold-filter to ~23 candidates (all positive
// -> raw float bits are a monotone u32 key), compact to wave-private LDS via
// ballot/mbcnt, then all-pairs rank over c<=64 candidates. Exact tie-break
// (lower index wins) via ~idx packed in the low 32 bits of the u64 key.
// Wave-uniform fallback to the full 5-round butterfly when c<5 or c>CAP.
// UNCHANGED from previous round: modeled BW-bound at ~10-12 us (64 MB
// mandatory read @ ~6.3 TB/s); 4 in-flight dwordx4/wave x 8 waves/SIMD
// gives ~14x the in-flight bytes needed to cover HBM latency.
__global__ __launch_bounds__(256) void topk5_kernel(const float* __restrict__ in,
                                                    int* __restrict__ idx_out) {
    const int wave = threadIdx.x >> 6;
    const int lane = threadIdx.x & 63;
    const int row  = blockIdx.x * 4 + wave;   // 0..16383

    const float4* row4 = (const float4*)(in + (size_t)row * D_DIM);

    float vv[16];
#pragma unroll
    for (int j = 0; j < 4; ++j) {
        float4 v = row4[lane + 64 * j];       // coalesced 16B/lane
        vv[4 * j + 0] = v.x; vv[4 * j + 1] = v.y;
        vv[4 * j + 2] = v.z; vv[4 * j + 3] = v.w;
    }

    __shared__ unsigned long long cand[4][CAP];

    // --- filter + wave compaction ---
    unsigned int base = 0;
#pragma unroll
    for (int k = 0; k < 16; ++k) {
        const int j = k >> 2, c4 = k & 3;
        bool p = vv[k] > THRESH;
        unsigned long long m = __ballot(p);
        if (p) {
            unsigned int off = base +
                __builtin_amdgcn_mbcnt_hi((unsigned int)(m >> 32),
                    __builtin_amdgcn_mbcnt_lo((unsigned int)m, 0));
            unsigned int e = 4u * (lane + 64 * j) + c4;
            unsigned long long key =
                ((unsigned long long)__float_as_uint(vv[k]) << 32) | (unsigned int)~e;
            if (off < CAP) cand[wave][off] = key;
        }
        base += (unsigned int)__popcll(m);
    }
    const int c = (int)base;
    __threadfence_block();   // order LDS writes before wave-local reads

    if (c >= NTOP && c <= CAP) {
        // --- fast path: all-pairs rank among c candidates ---
        unsigned long long mykey = (lane < c) ? cand[wave][lane] : 0ULL;
        int rank = 0;
        for (int i = 0; i < c; ++i) {
            unsigned long long bk = __shfl(mykey, i);
            rank += (bk > mykey) ? 1 : 0;
        }
        if (lane < c && rank < NTOP) {
            unsigned int e = ~(unsigned int)mykey;
            idx_out[row * NTOP + rank] = (int)e;
        }
    } else {
        // --- fallback: exact 5-round masked butterfly (round-1 code) ---
        int eidx[16];
#pragma unroll
        for (int k = 0; k < 16; ++k) eidx[k] = 4 * (lane + 64 * (k >> 2)) + (k & 3);
        int chosen[NTOP];
#pragma unroll
        for (int it = 0; it < NTOP; ++it) {
            float bv = -FLT_MAX; int bi = 0x7fffffff;
#pragma unroll
            for (int k = 0; k < 16; ++k)
                if (vv[k] > bv) { bv = vv[k]; bi = eidx[k]; }
#pragma unroll
            for (int s = 1; s < 64; s <<= 1) {
                float ov = __shfl_xor(bv, s);
                int   oi = __shfl_xor(bi, s);
                if (ov > bv || (ov == bv && oi < bi)) { bv = ov; bi = oi; }
            }
            chosen[it] = bi;
#pragma unroll
            for (int k = 0; k < 16; ++k)
                if (eidx[k] == bi) vv[k] = -FLT_MAX;
        }
        if (lane < NTOP) idx_out[row * NTOP + lane] = chosen[lane];
    }
}

// Stage 2 (restructured): ONE block per output batch b. Build the FULL
// 1088-bin histogram in LDS (every gathered index lands -> no window guard,
// no discarded atomics), then 65-tap convolution, 4 outputs/thread.
// vs previous 4-blocks/b windowed version: gather traffic /4, attempted
// LDS atomics 1.31M -> 82K. Numerics bitwise identical (same integer
// counts, same k=0..64 summation order).
__global__ __launch_bounds__(256) void conv_kernel(const int* __restrict__ idx_in,
                                                   float* __restrict__ out) {
    const int b   = blockIdx.x;               // 0..15 output batch
    const int tid = threadIdx.x;

    __shared__ float hist[D_DIM + 2 * RAD];   // bin j <-> pos = j - RAD
    __shared__ float w[2 * RAD + 1];

    for (int i = tid; i < D_DIM + 2 * RAD; i += 256) hist[i] = 0.0f;
    if (tid < 2 * RAD + 1) {
        int k = tid - RAD;
        w[tid] = NORM_C * expf(-0.125f * (float)(k * k));
    }
    __syncthreads();

    // gather: output batch b sums tops of t in [64b, 64b+64) across ALL input
    // batches b2 (faithful to the reference's [T,B,n]->[B,T*n] raw reshape).
    // 5120 ints = 1280 int4, coalesced; every index is in [0,1024) -> no guard.
    for (int i = tid; i < B_DIM * 80; i += 256) {
        int b2 = i / 80;
        int r4 = i % 80;
        const int4* p = (const int4*)(idx_in + ((size_t)b2 * T_DIM + 64 * b) * NTOP);
        int4 pos = p[r4];
        atomicAdd(&hist[pos.x + RAD], 1.0f);
        atomicAdd(&hist[pos.y + RAD], 1.0f);
        atomicAdd(&hist[pos.z + RAD], 1.0f);
        atomicAdd(&hist[pos.w + RAD], 1.0f);
    }
    __syncthreads();

    // out[b, d] = sum_k hist[d + k] * w[k]   (diff = RAD - k, exact; pdf symmetric)
#pragma unroll
    for (int q = 0; q < 4; ++q) {
        const int d = tid + 256 * q;
        float acc = 0.0f;
        for (int k = 0; k <= 2 * RAD; ++k)
            acc += hist[d + k] * w[k];
        out[(size_t)b * D_DIM + d] = acc;
    }
}

extern "C" void kernel_launch(void* const* d_in, const int* in_sizes, int n_in,
                              void* d_out, int out_size, void* d_ws, size_t ws_size,
                              hipStream_t stream) {
    const float* in  = (const float*)d_in[0];
    float*       out = (float*)d_out;
    int*         idx = (int*)d_ws;   // 16384*5 ints = 320 KB

    topk5_kernel<<<(B_DIM * T_DIM) / 4, 256, 0, stream>>>(in, idx);
    conv_kernel<<<B_DIM, 256, 0, stream>>>(idx, out);
}

// Round 2
// 94.969 us; speedup vs baseline: 1.0624x; 1.0624x over previous
//
#include <hip/hip_runtime.h>
#include <float.h>

#define D_DIM 1024
#define T_DIM 1024
#define B_DIM 16
#define NTOP 5
#define RAD 32              // exp(-k^2/8) == 0.0f in fp32 for |k| >= 29; 32 is safely exact
#define NORM_C 0.19947114f  // np.float32(1/(2*sqrt(2*pi)))
#define THRESH 2.0f         // 5th order stat of 1024 N(0,1) ~ 2.6; P(<5 qualifiers) ~ 3e-7/row
#define CAP 64              // max candidates/row handled on fast path (mean ~23)

// Stage 1: one wave per row. Threshold-filter to ~23 candidates (all positive
// -> raw float bits are a monotone u32 key), compact to wave-private LDS via
// ballot/mbcnt, then all-pairs rank over c<=64 candidates. Exact tie-break
// (lower index wins) via ~idx packed in the low 32 bits of the u64 key.
// Wave-uniform fallback to the full 5-round butterfly when c<5 or c>CAP.
// At the mandatory-read BW floor: 64 MB @ ~6.3 TB/s ~= 10.2 us.
__global__ __launch_bounds__(256) void topk5_kernel(const float* __restrict__ in,
                                                    int* __restrict__ idx_out) {
    const int wave = threadIdx.x >> 6;
    const int lane = threadIdx.x & 63;
    const int row  = blockIdx.x * 4 + wave;   // 0..16383

    const float4* row4 = (const float4*)(in + (size_t)row * D_DIM);

    float vv[16];
#pragma unroll
    for (int j = 0; j < 4; ++j) {
        float4 v = row4[lane + 64 * j];       // coalesced 16B/lane
        vv[4 * j + 0] = v.x; vv[4 * j + 1] = v.y;
        vv[4 * j + 2] = v.z; vv[4 * j + 3] = v.w;
    }

    __shared__ unsigned long long cand[4][CAP];

    // --- filter + wave compaction ---
    unsigned int base = 0;
#pragma unroll
    for (int k = 0; k < 16; ++k) {
        const int j = k >> 2, c4 = k & 3;
        bool p = vv[k] > THRESH;
        unsigned long long m = __ballot(p);
        if (p) {
            unsigned int off = base +
                __builtin_amdgcn_mbcnt_hi((unsigned int)(m >> 32),
                    __builtin_amdgcn_mbcnt_lo((unsigned int)m, 0));
            unsigned int e = 4u * (lane + 64 * j) + c4;
            unsigned long long key =
                ((unsigned long long)__float_as_uint(vv[k]) << 32) | (unsigned int)~e;
            if (off < CAP) cand[wave][off] = key;
        }
        base += (unsigned int)__popcll(m);
    }
    const int c = (int)base;
    __threadfence_block();   // order LDS writes before wave-local reads

    if (c >= NTOP && c <= CAP) {
        // --- fast path: all-pairs rank among c candidates ---
        unsigned long long mykey = (lane < c) ? cand[wave][lane] : 0ULL;
        int rank = 0;
        for (int i = 0; i < c; ++i) {
            unsigned long long bk = __shfl(mykey, i);
            rank += (bk > mykey) ? 1 : 0;
        }
        if (lane < c && rank < NTOP) {
            unsigned int e = ~(unsigned int)mykey;
            idx_out[row * NTOP + rank] = (int)e;
        }
    } else {
        // --- fallback: exact 5-round masked butterfly (round-1 code) ---
        int eidx[16];
#pragma unroll
        for (int k = 0; k < 16; ++k) eidx[k] = 4 * (lane + 64 * (k >> 2)) + (k & 3);
        int chosen[NTOP];
#pragma unroll
        for (int it = 0; it < NTOP; ++it) {
            float bv = -FLT_MAX; int bi = 0x7fffffff;
#pragma unroll
            for (int k = 0; k < 16; ++k)
                if (vv[k] > bv) { bv = vv[k]; bi = eidx[k]; }
#pragma unroll
            for (int s = 1; s < 64; s <<= 1) {
                float ov = __shfl_xor(bv, s);
                int   oi = __shfl_xor(bi, s);
                if (ov > bv || (ov == bv && oi < bi)) { bv = ov; bi = oi; }
            }
            chosen[it] = bi;
#pragma unroll
            for (int k = 0; k < 16; ++k)
                if (eidx[k] == bi) vv[k] = -FLT_MAX;
        }
        if (lane < NTOP) idx_out[row * NTOP + lane] = chosen[lane];
    }
}

// Stage 2 (REVERTED to the round-0 measured-94.6us config): 4 blocks per
// output row b; each block covers 256 outputs with a 320-bin windowed LDS
// histogram, then convolves with the truncated Gaussian.
// Post-mortem of the 16-block full-histogram variant (+6.3 us): conv is
// per-block serial-latency-bound, NOT atomic-count-bound. 64 blocks on 256
// CUs are fully concurrent; runtime = per-block latency, which the 4x-work
// variant quadrupled (2.1 -> 8.4 us). The per-block gather (1280 int4 from
// L2) is replicated across window-blocks regardless of window width, so
// further block-splitting saves only the ~260-cycle tap loop: not worth it.
__global__ __launch_bounds__(256) void conv_kernel(const int* __restrict__ idx_in,
                                                   float* __restrict__ out) {
    const int b   = blockIdx.x >> 2;          // 0..15
    const int d0  = (blockIdx.x & 3) * 256;   // output slice start
    const int tid = threadIdx.x;

    __shared__ float hist[256 + 2 * RAD];     // bin 0 <-> pos = d0 - RAD
    __shared__ float w[2 * RAD + 1];

    hist[tid] = 0.0f;
    if (tid < 2 * RAD) hist[256 + tid] = 0.0f;
    if (tid < 2 * RAD + 1) {
        int k = tid - RAD;
        w[tid] = NORM_C * expf(-0.125f * (float)(k * k));
    }
    __syncthreads();

    // gather: indices for row b are at (b2*T_DIM + 64*b)*NTOP + r, r in [0,320)
    // per b2; 320 ints are int4-aligned (320 = 80 * int4).
    for (int i = tid; i < B_DIM * 80; i += 256) {
        int b2 = i / 80;
        int r4 = i % 80;
        const int4* p = (const int4*)(idx_in + ((size_t)b2 * T_DIM + 64 * b) * NTOP);
        int4 pos = p[r4];
        unsigned int l0 = (unsigned int)(pos.x - d0 + RAD);
        unsigned int l1 = (unsigned int)(pos.y - d0 + RAD);
        unsigned int l2 = (unsigned int)(pos.z - d0 + RAD);
        unsigned int l3 = (unsigned int)(pos.w - d0 + RAD);
        if (l0 < 256 + 2 * RAD) atomicAdd(&hist[l0], 1.0f);
        if (l1 < 256 + 2 * RAD) atomicAdd(&hist[l1], 1.0f);
        if (l2 < 256 + 2 * RAD) atomicAdd(&hist[l2], 1.0f);
        if (l3 < 256 + 2 * RAD) atomicAdd(&hist[l3], 1.0f);
    }
    __syncthreads();

    // out[b, d0+tid] = sum_k hist[tid+k] * w[k]  (diff = RAD - k, exact)
    float acc = 0.0f;
    for (int k = 0; k <= 2 * RAD; ++k)
        acc += hist[tid + k] * w[k];
    out[(size_t)b * D_DIM + d0 + tid] = acc;
}

extern "C" void kernel_launch(void* const* d_in, const int* in_sizes, int n_in,
                              void* d_out, int out_size, void* d_ws, size_t ws_size,
                              hipStream_t stream) {
    const float* in  = (const float*)d_in[0];
    float*       out = (float*)d_out;
    int*         idx = (int*)d_ws;   // 16384*5 ints = 320 KB

    topk5_kernel<<<(B_DIM * T_DIM) / 4, 256, 0, stream>>>(in, idx);
    conv_kernel<<<B_DIM * 4, 256, 0, stream>>>(idx, out);
}